// Round 13
// baseline (345.288 us; speedup 1.0000x reference)
//
#include <hip/hip_runtime.h>

// B=8,H=8,S=1024,D=64 fp32 attention, raw-exp softmax, multiplicative key mask.
// Outputs: context[64,1024,64] then scores[64,1024,1024], both fp32.
// R13: producer-consumer wave specialization. 512-thr blocks: waves 0-3 compute
// (16 rows x 512 keys each, R11-style, E -> LDS dbuf), waves 4-7 flush the
// previous tile (full-line nt stores). 4 tiles of 32 rows per block; one
// barrier per phase. Stores overlap compute for ~4/5 of the kernel.
// Established: nt > plain (R9 101 vs R12 111); flush must be LDS-staged
// full-line (R11); one-ahead prefetch essential (R9).

typedef float    f32x4 __attribute__((ext_vector_type(4)));
typedef _Float16 f16x8 __attribute__((ext_vector_type(8)));
typedef _Float16 f16x4 __attribute__((ext_vector_type(4)));

#define MFMA32(A, B, C) __builtin_amdgcn_mfma_f32_16x16x32_f16((A), (B), (C), 0, 0, 0)
#define MFMA16(A, B, C) __builtin_amdgcn_mfma_f32_16x16x16f16((A), (B), (C), 0, 0, 0)

#define BHN 64
#define SEQ 1024
#define DIM 64

__device__ inline f16x8 cvt8(f32x4 a, f32x4 b) {
    f16x8 r;
    r[0] = (_Float16)a[0]; r[1] = (_Float16)a[1]; r[2] = (_Float16)a[2]; r[3] = (_Float16)a[3];
    r[4] = (_Float16)b[0]; r[5] = (_Float16)b[1]; r[6] = (_Float16)b[2]; r[7] = (_Float16)b[3];
    return r;
}

// Pre-pass: K -> f16 same layout; V -> f16 repacked for PV:
// VTP[bh][ktg][lane][e], e=c*4+j : V[bh][ktg*16 + (lane>>4)*4 + j][c*16 + (lane&15)]
__global__ __launch_bounds__(256)
void cvt_kv(const float* __restrict__ K, const float* __restrict__ V,
            _Float16* __restrict__ Kh, _Float16* __restrict__ VTP)
{
    __shared__ _Float16 tile[128 * 65];
    const int bh = blockIdx.x >> 3;
    const int kc = blockIdx.x & 7;
    const int t  = threadIdx.x;
    const size_t base = ((size_t)bh * SEQ + (size_t)kc * 128) * DIM;

    for (int it = 0; it < 8; ++it) {
        int idx = it * 256 + t;
        int key = idx >> 4;
        int c4  = idx & 15;
        f32x4 kv = *(const f32x4*)(K + base + key * DIM + c4 * 4);
        f32x4 vv = *(const f32x4*)(V + base + key * DIM + c4 * 4);
        f16x4 kh4;
        kh4[0] = (_Float16)kv[0]; kh4[1] = (_Float16)kv[1];
        kh4[2] = (_Float16)kv[2]; kh4[3] = (_Float16)kv[3];
        *(f16x4*)(Kh + base + key * DIM + c4 * 4) = kh4;
        tile[key * 65 + c4 * 4 + 0] = (_Float16)vv[0];
        tile[key * 65 + c4 * 4 + 1] = (_Float16)vv[1];
        tile[key * 65 + c4 * 4 + 2] = (_Float16)vv[2];
        tile[key * 65 + c4 * 4 + 3] = (_Float16)vv[3];
    }
    __syncthreads();
    for (int it = 0; it < 8; ++it) {
        int flat = it * 256 + t;
        int ktl  = flat >> 8;
        int rem  = flat & 255;
        int l    = rem >> 2;
        int c    = rem & 3;
        f16x4 o;
        #pragma unroll
        for (int j = 0; j < 4; ++j)
            o[j] = tile[(ktl * 16 + ((l >> 4) << 2) + j) * 65 + c * 16 + (l & 15)];
        *(f16x4*)(VTP + (((size_t)bh * 64 + kc * 8 + ktl) * 64 + l) * 16 + c * 4) = o;
    }
}

// Main kernel. 512 blocks x 512 thr (8 waves). Block = 128 q-rows of one (b,h),
// processed as 4 tiles of 32 rows, double-buffered through LDS.
// Producer wave w(0-3): pq=w>>1 rows, khf=w&1 key half; swapped QK^T.
// Consumer wave (4-7): flushes tile t-1 (8 rows each) with nt full-line stores.
template <bool PRECONV>
__global__ __launch_bounds__(512, 2)
void attn_main(const float* __restrict__ Q, const float* __restrict__ K,
               const float* __restrict__ V, const float* __restrict__ mask,
               const _Float16* __restrict__ Kh, const _Float16* __restrict__ VTP,
               float* __restrict__ ctx, float* __restrict__ scores)
{
    __shared__ _Float16 Ebuf[2][32][1024];     // 128 KB, double-buffered E
    __shared__ float rs[2][2][2][16];          // [buf][pq][khf][col] rowsum partials
    __shared__ float cbuf[2][2][16][64];       // [buf][pq][e][lane] PV partials (khf=1)

    const int bid = blockIdx.x;
    const int wg  = ((bid & 7) << 6) | (bid >> 3);   // XCD-bijective (512 % 8 == 0)
    const int bh  = wg >> 3;
    const int qg  = wg & 7;                          // 128-row group
    const int b   = bh >> 3;
    const int w    = threadIdx.x >> 6;
    const int lane = threadIdx.x & 63;
    const int col  = lane & 15;
    const int g    = lane >> 4;
    const float scale = 0.125f;

    if (w < 4) {
        // ======================= producers =======================
        const int pq  = w >> 1;
        const int khf = w & 1;
        const int kb  = khf * 512;
        const float* mb = mask + (size_t)b * SEQ + kb;
        const _Float16* kbase = Kh + ((size_t)bh * SEQ + kb + col) * DIM + g * 8;
        const _Float16* vtpb  = VTP + (((size_t)bh * 64 + khf * 32) * 64 + lane) * 16;

        f32x4 cprev[4];
        #pragma unroll
        for (int dt = 0; dt < 4; ++dt) cprev[dt] = (f32x4){0.f, 0.f, 0.f, 0.f};

        for (int t = 0; t < 4; ++t) {
            const int p  = t & 1;
            const int q0 = qg * 128 + t * 32;

            // finalize ctx of tile t-1 (khf==0 only; partner data crossed barrier)
            if (khf == 0 && t > 0) {
                const int pb  = (t - 1) & 1;
                const int q0p = qg * 128 + (t - 1) * 32;
                const float inv = 1.0f / (rs[pb][pq][0][col] + rs[pb][pq][1][col] + 1e-8f);
                #pragma unroll
                for (int dt = 0; dt < 4; ++dt) {
                    f32x4 r = cprev[dt];
                    #pragma unroll
                    for (int i = 0; i < 4; ++i) r[i] += cbuf[pb][pq][dt * 4 + i][lane];
                    r[0] *= inv; r[1] *= inv; r[2] *= inv; r[3] *= inv;
                    *(f32x4*)(ctx + ((size_t)bh * SEQ + q0p + pq * 16 + col) * DIM + dt * 16 + g * 4) = r;
                }
            }

            // ---- compute tile t
            f16x8 qf0, qf1;
            {
                const float* qp = Q + ((size_t)bh * SEQ + q0 + pq * 16 + col) * DIM + g * 8;
                qf0 = cvt8(*(const f32x4*)qp,        *(const f32x4*)(qp + 4));
                qf1 = cvt8(*(const f32x4*)(qp + 32), *(const f32x4*)(qp + 36));
            }
            f32x4 cacc[4];
            #pragma unroll
            for (int dt = 0; dt < 4; ++dt) cacc[dt] = (f32x4){0.f, 0.f, 0.f, 0.f};
            float rsum = 0.f;
            char* ebR = (char*)Ebuf[p] + (pq * 16 + col) * 2048;
            const int rx = (col & 3) << 2;   // row-XOR for granule swizzle

            f16x8 k0, k1, va, vb;
            f32x4 m4;
            if (PRECONV) {
                k0 = *(const f16x8*)(kbase);
                k1 = *(const f16x8*)(kbase + 32);
                va = *(const f16x8*)(vtpb);
                vb = *(const f16x8*)(vtpb + 8);
            } else {
                const float* kp = K + ((size_t)bh * SEQ + kb + col) * DIM + g * 8;
                k0 = cvt8(*(const f32x4*)kp,        *(const f32x4*)(kp + 4));
                k1 = cvt8(*(const f32x4*)(kp + 32), *(const f32x4*)(kp + 36));
                #pragma unroll
                for (int e = 0; e < 8; ++e) {
                    va[e] = (_Float16)V[((size_t)bh * SEQ + kb + g * 4 + (e & 3)) * DIM + (e >> 2) * 16 + col];
                    vb[e] = (_Float16)V[((size_t)bh * SEQ + kb + g * 4 + (e & 3)) * DIM + (2 + (e >> 2)) * 16 + col];
                }
            }
            m4 = *(const f32x4*)(mb + g * 4);

            #pragma unroll
            for (int kt = 0; kt < 32; ++kt) {
                const int ktn = (kt + 1) & 31;
                f16x8 n0, n1, nva, nvb;
                if (PRECONV) {
                    n0  = *(const f16x8*)(kbase + (size_t)ktn * 16 * DIM);
                    n1  = *(const f16x8*)(kbase + (size_t)ktn * 16 * DIM + 32);
                    nva = *(const f16x8*)(vtpb + (size_t)ktn * 64 * 16);
                    nvb = *(const f16x8*)(vtpb + (size_t)ktn * 64 * 16 + 8);
                } else {
                    const float* kp = K + ((size_t)bh * SEQ + kb + ktn * 16 + col) * DIM + g * 8;
                    n0 = cvt8(*(const f32x4*)kp,        *(const f32x4*)(kp + 4));
                    n1 = cvt8(*(const f32x4*)(kp + 32), *(const f32x4*)(kp + 36));
                    #pragma unroll
                    for (int e = 0; e < 8; ++e) {
                        nva[e] = (_Float16)V[((size_t)bh * SEQ + kb + ktn * 16 + g * 4 + (e & 3)) * DIM + (e >> 2) * 16 + col];
                        nvb[e] = (_Float16)V[((size_t)bh * SEQ + kb + ktn * 16 + g * 4 + (e & 3)) * DIM + (2 + (e >> 2)) * 16 + col];
                    }
                }
                f32x4 nm = *(const f32x4*)(mb + ktn * 16 + g * 4);

                f32x4 acc = {0.f, 0.f, 0.f, 0.f};
                acc = MFMA32(k0, qf0, acc);
                acc = MFMA32(k1, qf1, acc);
                const float e0 = __expf(acc[0] * scale) * m4[0];
                const float e1 = __expf(acc[1] * scale) * m4[1];
                const float e2 = __expf(acc[2] * scale) * m4[2];
                const float e3 = __expf(acc[3] * scale) * m4[3];
                rsum += e0 + e1 + e2 + e3;
                f16x4 pf;
                pf[0] = (_Float16)e0; pf[1] = (_Float16)e1;
                pf[2] = (_Float16)e2; pf[3] = (_Float16)e3;
                const int kg = (khf * 128 + kt * 4 + g) ^ rx;
                *(f16x4*)(ebR + kg * 8) = pf;

                {
                    f16x4 vt0 = __builtin_shufflevector(va, va, 0, 1, 2, 3);
                    f16x4 vt1 = __builtin_shufflevector(va, va, 4, 5, 6, 7);
                    f16x4 vt2 = __builtin_shufflevector(vb, vb, 0, 1, 2, 3);
                    f16x4 vt3 = __builtin_shufflevector(vb, vb, 4, 5, 6, 7);
                    cacc[0] = MFMA16(vt0, pf, cacc[0]);
                    cacc[1] = MFMA16(vt1, pf, cacc[1]);
                    cacc[2] = MFMA16(vt2, pf, cacc[2]);
                    cacc[3] = MFMA16(vt3, pf, cacc[3]);
                }
                k0 = n0; k1 = n1; va = nva; vb = nvb; m4 = nm;
            }

            rsum += __shfl_xor(rsum, 16, 64);
            rsum += __shfl_xor(rsum, 32, 64);
            if (g == 0) rs[p][pq][khf][col] = rsum;

            if (khf == 1) {
                #pragma unroll
                for (int dt = 0; dt < 4; ++dt)
                    #pragma unroll
                    for (int i = 0; i < 4; ++i)
                        cbuf[p][pq][dt * 4 + i][lane] = cacc[dt][i];
            } else {
                #pragma unroll
                for (int dt = 0; dt < 4; ++dt) cprev[dt] = cacc[dt];
            }
            __syncthreads();
        }

        // drain: finalize ctx of tile 3
        if (khf == 0) {
            const float inv = 1.0f / (rs[1][pq][0][col] + rs[1][pq][1][col] + 1e-8f);
            const int q0p = qg * 128 + 3 * 32;
            #pragma unroll
            for (int dt = 0; dt < 4; ++dt) {
                f32x4 r = cprev[dt];
                #pragma unroll
                for (int i = 0; i < 4; ++i) r[i] += cbuf[1][pq][dt * 4 + i][lane];
                r[0] *= inv; r[1] *= inv; r[2] *= inv; r[3] *= inv;
                *(f32x4*)(ctx + ((size_t)bh * SEQ + q0p + pq * 16 + col) * DIM + dt * 16 + g * 4) = r;
            }
        }
    } else {
        // ======================= consumers =======================
        const int cw = w - 4;
        for (int t = 0; t < 4; ++t) {
            if (t > 0) {
                const int pb  = (t - 1) & 1;
                const int q0p = qg * 128 + (t - 1) * 32;
                char* eb = (char*)Ebuf[pb];
                #pragma unroll
                for (int j = 0; j < 8; ++j) {
                    const int r = cw * 8 + j;
                    const float inv = 1.0f / (rs[pb][r >> 4][0][r & 15] + rs[pb][r >> 4][1][r & 15] + 1e-8f);
                    f16x4 ev[4];
                    #pragma unroll
                    for (int q = 0; q < 4; ++q) {
                        const int kg = (q * 64 + lane) ^ ((r & 3) << 2);
                        ev[q] = *(const f16x4*)(eb + r * 2048 + kg * 8);
                    }
                    float* dst = scores + ((size_t)bh * SEQ + q0p + r) * SEQ + lane * 4;
                    #pragma unroll
                    for (int q = 0; q < 4; ++q) {
                        f32x4 o;
                        o[0] = (float)ev[q][0] * inv;
                        o[1] = (float)ev[q][1] * inv;
                        o[2] = (float)ev[q][2] * inv;
                        o[3] = (float)ev[q][3] * inv;
                        __builtin_nontemporal_store(o, (f32x4*)(dst + q * 256));
                    }
                }
            }
            __syncthreads();
        }
        // drain: flush tile 3
        {
            const int q0p = qg * 128 + 3 * 32;
            char* eb = (char*)Ebuf[1];
            #pragma unroll
            for (int j = 0; j < 8; ++j) {
                const int r = cw * 8 + j;
                const float inv = 1.0f / (rs[1][r >> 4][0][r & 15] + rs[1][r >> 4][1][r & 15] + 1e-8f);
                f16x4 ev[4];
                #pragma unroll
                for (int q = 0; q < 4; ++q) {
                    const int kg = (q * 64 + lane) ^ ((r & 3) << 2);
                    ev[q] = *(const f16x4*)(eb + r * 2048 + kg * 8);
                }
                float* dst = scores + ((size_t)bh * SEQ + q0p + r) * SEQ + lane * 4;
                #pragma unroll
                for (int q = 0; q < 4; ++q) {
                    f32x4 o;
                    o[0] = (float)ev[q][0] * inv;
                    o[1] = (float)ev[q][1] * inv;
                    o[2] = (float)ev[q][2] * inv;
                    o[3] = (float)ev[q][3] * inv;
                    __builtin_nontemporal_store(o, (f32x4*)(dst + q * 256));
                }
            }
        }
    }
}

extern "C" void kernel_launch(void* const* d_in, const int* in_sizes, int n_in,
                              void* d_out, int out_size, void* d_ws, size_t ws_size,
                              hipStream_t stream)
{
    const float* Q    = (const float*)d_in[0];
    const float* K    = (const float*)d_in[1];
    const float* V    = (const float*)d_in[2];
    const float* mask = (const float*)d_in[3];
    float* ctx    = (float*)d_out;
    float* scores = ctx + (size_t)BHN * SEQ * DIM;

    const size_t elems = (size_t)BHN * SEQ * DIM;       // 4,194,304
    const size_t need  = elems * 2 * sizeof(_Float16);  // Kh + VTP = 16 MB
    if (ws_size >= need) {
        _Float16* Kh  = (_Float16*)d_ws;
        _Float16* VTP = Kh + elems;
        cvt_kv<<<512, 256, 0, stream>>>(K, V, Kh, VTP);
        attn_main<true><<<512, 512, 0, stream>>>(Q, K, V, mask, Kh, VTP, ctx, scores);
    } else {
        attn_main<false><<<512, 512, 0, stream>>>(Q, K, V, mask, nullptr, nullptr, ctx, scores);
    }
}

// Round 14
// 344.948 us; speedup vs baseline: 1.0010x; 1.0010x over previous
//
#include <hip/hip_runtime.h>

// B=8,H=8,S=1024,D=64 fp32 attention, raw-exp softmax, multiplicative key mask.
// Outputs: context[64,1024,64] then scores[64,1024,1024], both fp32.
// R14 = R13 with ONE fix: __launch_bounds__(512,1) instead of (512,2).
// R13's (512,2) capped VGPR at 128 -> producer path spilled (FETCH 537 MB,
// WRITE 542 MB of scratch round-trip). LDS is 148 KB = 1 block/CU anyway,
// so the cap bought nothing. Producer-consumer theory gets its real test.

typedef float    f32x4 __attribute__((ext_vector_type(4)));
typedef _Float16 f16x8 __attribute__((ext_vector_type(8)));
typedef _Float16 f16x4 __attribute__((ext_vector_type(4)));

#define MFMA32(A, B, C) __builtin_amdgcn_mfma_f32_16x16x32_f16((A), (B), (C), 0, 0, 0)
#define MFMA16(A, B, C) __builtin_amdgcn_mfma_f32_16x16x16f16((A), (B), (C), 0, 0, 0)

#define BHN 64
#define SEQ 1024
#define DIM 64

__device__ inline f16x8 cvt8(f32x4 a, f32x4 b) {
    f16x8 r;
    r[0] = (_Float16)a[0]; r[1] = (_Float16)a[1]; r[2] = (_Float16)a[2]; r[3] = (_Float16)a[3];
    r[4] = (_Float16)b[0]; r[5] = (_Float16)b[1]; r[6] = (_Float16)b[2]; r[7] = (_Float16)b[3];
    return r;
}

// Pre-pass: K -> f16 same layout; V -> f16 repacked for PV:
// VTP[bh][ktg][lane][e], e=c*4+j : V[bh][ktg*16 + (lane>>4)*4 + j][c*16 + (lane&15)]
__global__ __launch_bounds__(256)
void cvt_kv(const float* __restrict__ K, const float* __restrict__ V,
            _Float16* __restrict__ Kh, _Float16* __restrict__ VTP)
{
    __shared__ _Float16 tile[128 * 65];
    const int bh = blockIdx.x >> 3;
    const int kc = blockIdx.x & 7;
    const int t  = threadIdx.x;
    const size_t base = ((size_t)bh * SEQ + (size_t)kc * 128) * DIM;

    for (int it = 0; it < 8; ++it) {
        int idx = it * 256 + t;
        int key = idx >> 4;
        int c4  = idx & 15;
        f32x4 kv = *(const f32x4*)(K + base + key * DIM + c4 * 4);
        f32x4 vv = *(const f32x4*)(V + base + key * DIM + c4 * 4);
        f16x4 kh4;
        kh4[0] = (_Float16)kv[0]; kh4[1] = (_Float16)kv[1];
        kh4[2] = (_Float16)kv[2]; kh4[3] = (_Float16)kv[3];
        *(f16x4*)(Kh + base + key * DIM + c4 * 4) = kh4;
        tile[key * 65 + c4 * 4 + 0] = (_Float16)vv[0];
        tile[key * 65 + c4 * 4 + 1] = (_Float16)vv[1];
        tile[key * 65 + c4 * 4 + 2] = (_Float16)vv[2];
        tile[key * 65 + c4 * 4 + 3] = (_Float16)vv[3];
    }
    __syncthreads();
    for (int it = 0; it < 8; ++it) {
        int flat = it * 256 + t;
        int ktl  = flat >> 8;
        int rem  = flat & 255;
        int l    = rem >> 2;
        int c    = rem & 3;
        f16x4 o;
        #pragma unroll
        for (int j = 0; j < 4; ++j)
            o[j] = tile[(ktl * 16 + ((l >> 4) << 2) + j) * 65 + c * 16 + (l & 15)];
        *(f16x4*)(VTP + (((size_t)bh * 64 + kc * 8 + ktl) * 64 + l) * 16 + c * 4) = o;
    }
}

// Main kernel. 512 blocks x 512 thr (8 waves). Block = 128 q-rows of one (b,h),
// processed as 4 tiles of 32 rows, double-buffered through LDS.
// Producer wave w(0-3): pq=w>>1 rows, khf=w&1 key half; swapped QK^T.
// Consumer wave (4-7): flushes tile t-1 (8 rows each) with nt full-line stores.
template <bool PRECONV>
__global__ __launch_bounds__(512, 1)
void attn_main(const float* __restrict__ Q, const float* __restrict__ K,
               const float* __restrict__ V, const float* __restrict__ mask,
               const _Float16* __restrict__ Kh, const _Float16* __restrict__ VTP,
               float* __restrict__ ctx, float* __restrict__ scores)
{
    __shared__ _Float16 Ebuf[2][32][1024];     // 128 KB, double-buffered E
    __shared__ float rs[2][2][2][16];          // [buf][pq][khf][col] rowsum partials
    __shared__ float cbuf[2][2][16][64];       // [buf][pq][e][lane] PV partials (khf=1)

    const int bid = blockIdx.x;
    const int wg  = ((bid & 7) << 6) | (bid >> 3);   // XCD-bijective (512 % 8 == 0)
    const int bh  = wg >> 3;
    const int qg  = wg & 7;                          // 128-row group
    const int b   = bh >> 3;
    const int w    = threadIdx.x >> 6;
    const int lane = threadIdx.x & 63;
    const int col  = lane & 15;
    const int g    = lane >> 4;
    const float scale = 0.125f;

    if (w < 4) {
        // ======================= producers =======================
        const int pq  = w >> 1;
        const int khf = w & 1;
        const int kb  = khf * 512;
        const float* mb = mask + (size_t)b * SEQ + kb;
        const _Float16* kbase = Kh + ((size_t)bh * SEQ + kb + col) * DIM + g * 8;
        const _Float16* vtpb  = VTP + (((size_t)bh * 64 + khf * 32) * 64 + lane) * 16;

        f32x4 cprev[4];
        #pragma unroll
        for (int dt = 0; dt < 4; ++dt) cprev[dt] = (f32x4){0.f, 0.f, 0.f, 0.f};

        for (int t = 0; t < 4; ++t) {
            const int p  = t & 1;
            const int q0 = qg * 128 + t * 32;

            // finalize ctx of tile t-1 (khf==0 only; partner data crossed barrier)
            if (khf == 0 && t > 0) {
                const int pb  = (t - 1) & 1;
                const int q0p = qg * 128 + (t - 1) * 32;
                const float inv = 1.0f / (rs[pb][pq][0][col] + rs[pb][pq][1][col] + 1e-8f);
                #pragma unroll
                for (int dt = 0; dt < 4; ++dt) {
                    f32x4 r = cprev[dt];
                    #pragma unroll
                    for (int i = 0; i < 4; ++i) r[i] += cbuf[pb][pq][dt * 4 + i][lane];
                    r[0] *= inv; r[1] *= inv; r[2] *= inv; r[3] *= inv;
                    *(f32x4*)(ctx + ((size_t)bh * SEQ + q0p + pq * 16 + col) * DIM + dt * 16 + g * 4) = r;
                }
            }

            // ---- compute tile t
            f16x8 qf0, qf1;
            {
                const float* qp = Q + ((size_t)bh * SEQ + q0 + pq * 16 + col) * DIM + g * 8;
                qf0 = cvt8(*(const f32x4*)qp,        *(const f32x4*)(qp + 4));
                qf1 = cvt8(*(const f32x4*)(qp + 32), *(const f32x4*)(qp + 36));
            }
            f32x4 cacc[4];
            #pragma unroll
            for (int dt = 0; dt < 4; ++dt) cacc[dt] = (f32x4){0.f, 0.f, 0.f, 0.f};
            float rsum = 0.f;
            char* ebR = (char*)Ebuf[p] + (pq * 16 + col) * 2048;
            const int rx = (col & 3) << 2;   // row-XOR for granule swizzle

            f16x8 k0, k1, va, vb;
            f32x4 m4;
            if (PRECONV) {
                k0 = *(const f16x8*)(kbase);
                k1 = *(const f16x8*)(kbase + 32);
                va = *(const f16x8*)(vtpb);
                vb = *(const f16x8*)(vtpb + 8);
            } else {
                const float* kp = K + ((size_t)bh * SEQ + kb + col) * DIM + g * 8;
                k0 = cvt8(*(const f32x4*)kp,        *(const f32x4*)(kp + 4));
                k1 = cvt8(*(const f32x4*)(kp + 32), *(const f32x4*)(kp + 36));
                #pragma unroll
                for (int e = 0; e < 8; ++e) {
                    va[e] = (_Float16)V[((size_t)bh * SEQ + kb + g * 4 + (e & 3)) * DIM + (e >> 2) * 16 + col];
                    vb[e] = (_Float16)V[((size_t)bh * SEQ + kb + g * 4 + (e & 3)) * DIM + (2 + (e >> 2)) * 16 + col];
                }
            }
            m4 = *(const f32x4*)(mb + g * 4);

            #pragma unroll
            for (int kt = 0; kt < 32; ++kt) {
                const int ktn = (kt + 1) & 31;
                f16x8 n0, n1, nva, nvb;
                if (PRECONV) {
                    n0  = *(const f16x8*)(kbase + (size_t)ktn * 16 * DIM);
                    n1  = *(const f16x8*)(kbase + (size_t)ktn * 16 * DIM + 32);
                    nva = *(const f16x8*)(vtpb + (size_t)ktn * 64 * 16);
                    nvb = *(const f16x8*)(vtpb + (size_t)ktn * 64 * 16 + 8);
                } else {
                    const float* kp = K + ((size_t)bh * SEQ + kb + ktn * 16 + col) * DIM + g * 8;
                    n0 = cvt8(*(const f32x4*)kp,        *(const f32x4*)(kp + 4));
                    n1 = cvt8(*(const f32x4*)(kp + 32), *(const f32x4*)(kp + 36));
                    #pragma unroll
                    for (int e = 0; e < 8; ++e) {
                        nva[e] = (_Float16)V[((size_t)bh * SEQ + kb + ktn * 16 + g * 4 + (e & 3)) * DIM + (e >> 2) * 16 + col];
                        nvb[e] = (_Float16)V[((size_t)bh * SEQ + kb + ktn * 16 + g * 4 + (e & 3)) * DIM + (2 + (e >> 2)) * 16 + col];
                    }
                }
                f32x4 nm = *(const f32x4*)(mb + ktn * 16 + g * 4);

                f32x4 acc = {0.f, 0.f, 0.f, 0.f};
                acc = MFMA32(k0, qf0, acc);
                acc = MFMA32(k1, qf1, acc);
                const float e0 = __expf(acc[0] * scale) * m4[0];
                const float e1 = __expf(acc[1] * scale) * m4[1];
                const float e2 = __expf(acc[2] * scale) * m4[2];
                const float e3 = __expf(acc[3] * scale) * m4[3];
                rsum += e0 + e1 + e2 + e3;
                f16x4 pf;
                pf[0] = (_Float16)e0; pf[1] = (_Float16)e1;
                pf[2] = (_Float16)e2; pf[3] = (_Float16)e3;
                const int kg = (khf * 128 + kt * 4 + g) ^ rx;
                *(f16x4*)(ebR + kg * 8) = pf;

                {
                    f16x4 vt0 = __builtin_shufflevector(va, va, 0, 1, 2, 3);
                    f16x4 vt1 = __builtin_shufflevector(va, va, 4, 5, 6, 7);
                    f16x4 vt2 = __builtin_shufflevector(vb, vb, 0, 1, 2, 3);
                    f16x4 vt3 = __builtin_shufflevector(vb, vb, 4, 5, 6, 7);
                    cacc[0] = MFMA16(vt0, pf, cacc[0]);
                    cacc[1] = MFMA16(vt1, pf, cacc[1]);
                    cacc[2] = MFMA16(vt2, pf, cacc[2]);
                    cacc[3] = MFMA16(vt3, pf, cacc[3]);
                }
                k0 = n0; k1 = n1; va = nva; vb = nvb; m4 = nm;
            }

            rsum += __shfl_xor(rsum, 16, 64);
            rsum += __shfl_xor(rsum, 32, 64);
            if (g == 0) rs[p][pq][khf][col] = rsum;

            if (khf == 1) {
                #pragma unroll
                for (int dt = 0; dt < 4; ++dt)
                    #pragma unroll
                    for (int i = 0; i < 4; ++i)
                        cbuf[p][pq][dt * 4 + i][lane] = cacc[dt][i];
            } else {
                #pragma unroll
                for (int dt = 0; dt < 4; ++dt) cprev[dt] = cacc[dt];
            }
            __syncthreads();
        }

        // drain: finalize ctx of tile 3
        if (khf == 0) {
            const float inv = 1.0f / (rs[1][pq][0][col] + rs[1][pq][1][col] + 1e-8f);
            const int q0p = qg * 128 + 3 * 32;
            #pragma unroll
            for (int dt = 0; dt < 4; ++dt) {
                f32x4 r = cprev[dt];
                #pragma unroll
                for (int i = 0; i < 4; ++i) r[i] += cbuf[1][pq][dt * 4 + i][lane];
                r[0] *= inv; r[1] *= inv; r[2] *= inv; r[3] *= inv;
                *(f32x4*)(ctx + ((size_t)bh * SEQ + q0p + pq * 16 + col) * DIM + dt * 16 + g * 4) = r;
            }
        }
    } else {
        // ======================= consumers =======================
        const int cw = w - 4;
        for (int t = 0; t < 4; ++t) {
            if (t > 0) {
                const int pb  = (t - 1) & 1;
                const int q0p = qg * 128 + (t - 1) * 32;
                char* eb = (char*)Ebuf[pb];
                #pragma unroll
                for (int j = 0; j < 8; ++j) {
                    const int r = cw * 8 + j;
                    const float inv = 1.0f / (rs[pb][r >> 4][0][r & 15] + rs[pb][r >> 4][1][r & 15] + 1e-8f);
                    f16x4 ev[4];
                    #pragma unroll
                    for (int q = 0; q < 4; ++q) {
                        const int kg = (q * 64 + lane) ^ ((r & 3) << 2);
                        ev[q] = *(const f16x4*)(eb + r * 2048 + kg * 8);
                    }
                    float* dst = scores + ((size_t)bh * SEQ + q0p + r) * SEQ + lane * 4;
                    #pragma unroll
                    for (int q = 0; q < 4; ++q) {
                        f32x4 o;
                        o[0] = (float)ev[q][0] * inv;
                        o[1] = (float)ev[q][1] * inv;
                        o[2] = (float)ev[q][2] * inv;
                        o[3] = (float)ev[q][3] * inv;
                        __builtin_nontemporal_store(o, (f32x4*)(dst + q * 256));
                    }
                }
            }
            __syncthreads();
        }
        // drain: flush tile 3
        {
            const int q0p = qg * 128 + 3 * 32;
            char* eb = (char*)Ebuf[1];
            #pragma unroll
            for (int j = 0; j < 8; ++j) {
                const int r = cw * 8 + j;
                const float inv = 1.0f / (rs[1][r >> 4][0][r & 15] + rs[1][r >> 4][1][r & 15] + 1e-8f);
                f16x4 ev[4];
                #pragma unroll
                for (int q = 0; q < 4; ++q) {
                    const int kg = (q * 64 + lane) ^ ((r & 3) << 2);
                    ev[q] = *(const f16x4*)(eb + r * 2048 + kg * 8);
                }
                float* dst = scores + ((size_t)bh * SEQ + q0p + r) * SEQ + lane * 4;
                #pragma unroll
                for (int q = 0; q < 4; ++q) {
                    f32x4 o;
                    o[0] = (float)ev[q][0] * inv;
                    o[1] = (float)ev[q][1] * inv;
                    o[2] = (float)ev[q][2] * inv;
                    o[3] = (float)ev[q][3] * inv;
                    __builtin_nontemporal_store(o, (f32x4*)(dst + q * 256));
                }
            }
        }
    }
}

extern "C" void kernel_launch(void* const* d_in, const int* in_sizes, int n_in,
                              void* d_out, int out_size, void* d_ws, size_t ws_size,
                              hipStream_t stream)
{
    const float* Q    = (const float*)d_in[0];
    const float* K    = (const float*)d_in[1];
    const float* V    = (const float*)d_in[2];
    const float* mask = (const float*)d_in[3];
    float* ctx    = (float*)d_out;
    float* scores = ctx + (size_t)BHN * SEQ * DIM;

    const size_t elems = (size_t)BHN * SEQ * DIM;       // 4,194,304
    const size_t need  = elems * 2 * sizeof(_Float16);  // Kh + VTP = 16 MB
    if (ws_size >= need) {
        _Float16* Kh  = (_Float16*)d_ws;
        _Float16* VTP = Kh + elems;
        cvt_kv<<<512, 256, 0, stream>>>(K, V, Kh, VTP);
        attn_main<true><<<512, 512, 0, stream>>>(Q, K, V, mask, Kh, VTP, ctx, scores);
    } else {
        attn_main<false><<<512, 512, 0, stream>>>(Q, K, V, mask, nullptr, nullptr, ctx, scores);
    }
}

// Round 15
// 125.945 us; speedup vs baseline: 2.7416x; 2.7389x over previous
//
#include <hip/hip_runtime.h>

// B=8,H=8,S=1024,D=64 fp32 attention, raw-exp softmax, multiplicative key mask.
// Outputs: context[64,1024,64] then scores[64,1024,1024], both fp32.
// R15 = R14 with ONE fix: the producer's 32-iteration kt loop is left ROLLED
// (no #pragma unroll). R10/R11/R13/R14 all fully unrolled prefetch loops ->
// register explosion -> scratch spill (FETCH 537 MB). R9's rolled loop is the
// proven-lean pattern. Producer-consumer overlap finally gets a clean test.

typedef float    f32x4 __attribute__((ext_vector_type(4)));
typedef _Float16 f16x8 __attribute__((ext_vector_type(8)));
typedef _Float16 f16x4 __attribute__((ext_vector_type(4)));

#define MFMA32(A, B, C) __builtin_amdgcn_mfma_f32_16x16x32_f16((A), (B), (C), 0, 0, 0)
#define MFMA16(A, B, C) __builtin_amdgcn_mfma_f32_16x16x16f16((A), (B), (C), 0, 0, 0)

#define BHN 64
#define SEQ 1024
#define DIM 64

__device__ inline f16x8 cvt8(f32x4 a, f32x4 b) {
    f16x8 r;
    r[0] = (_Float16)a[0]; r[1] = (_Float16)a[1]; r[2] = (_Float16)a[2]; r[3] = (_Float16)a[3];
    r[4] = (_Float16)b[0]; r[5] = (_Float16)b[1]; r[6] = (_Float16)b[2]; r[7] = (_Float16)b[3];
    return r;
}

// Pre-pass: K -> f16 same layout; V -> f16 repacked for PV:
// VTP[bh][ktg][lane][e], e=c*4+j : V[bh][ktg*16 + (lane>>4)*4 + j][c*16 + (lane&15)]
__global__ __launch_bounds__(256)
void cvt_kv(const float* __restrict__ K, const float* __restrict__ V,
            _Float16* __restrict__ Kh, _Float16* __restrict__ VTP)
{
    __shared__ _Float16 tile[128 * 65];
    const int bh = blockIdx.x >> 3;
    const int kc = blockIdx.x & 7;
    const int t  = threadIdx.x;
    const size_t base = ((size_t)bh * SEQ + (size_t)kc * 128) * DIM;

    for (int it = 0; it < 8; ++it) {
        int idx = it * 256 + t;
        int key = idx >> 4;
        int c4  = idx & 15;
        f32x4 kv = *(const f32x4*)(K + base + key * DIM + c4 * 4);
        f32x4 vv = *(const f32x4*)(V + base + key * DIM + c4 * 4);
        f16x4 kh4;
        kh4[0] = (_Float16)kv[0]; kh4[1] = (_Float16)kv[1];
        kh4[2] = (_Float16)kv[2]; kh4[3] = (_Float16)kv[3];
        *(f16x4*)(Kh + base + key * DIM + c4 * 4) = kh4;
        tile[key * 65 + c4 * 4 + 0] = (_Float16)vv[0];
        tile[key * 65 + c4 * 4 + 1] = (_Float16)vv[1];
        tile[key * 65 + c4 * 4 + 2] = (_Float16)vv[2];
        tile[key * 65 + c4 * 4 + 3] = (_Float16)vv[3];
    }
    __syncthreads();
    for (int it = 0; it < 8; ++it) {
        int flat = it * 256 + t;
        int ktl  = flat >> 8;
        int rem  = flat & 255;
        int l    = rem >> 2;
        int c    = rem & 3;
        f16x4 o;
        #pragma unroll
        for (int j = 0; j < 4; ++j)
            o[j] = tile[(ktl * 16 + ((l >> 4) << 2) + j) * 65 + c * 16 + (l & 15)];
        *(f16x4*)(VTP + (((size_t)bh * 64 + kc * 8 + ktl) * 64 + l) * 16 + c * 4) = o;
    }
}

// Main kernel. 512 blocks x 512 thr (8 waves). Block = 128 q-rows of one (b,h),
// processed as 4 tiles of 32 rows, double-buffered through LDS.
// Producer wave w(0-3): pq=w>>1 rows, khf=w&1 key half; swapped QK^T.
// Consumer wave (4-7): flushes tile t-1 (8 rows each) with nt full-line stores.
template <bool PRECONV>
__global__ __launch_bounds__(512, 1)
void attn_main(const float* __restrict__ Q, const float* __restrict__ K,
               const float* __restrict__ V, const float* __restrict__ mask,
               const _Float16* __restrict__ Kh, const _Float16* __restrict__ VTP,
               float* __restrict__ ctx, float* __restrict__ scores)
{
    __shared__ _Float16 Ebuf[2][32][1024];     // 128 KB, double-buffered E
    __shared__ float rs[2][2][2][16];          // [buf][pq][khf][col] rowsum partials
    __shared__ float cbuf[2][2][16][64];       // [buf][pq][e][lane] PV partials (khf=1)

    const int bid = blockIdx.x;
    const int wg  = ((bid & 7) << 6) | (bid >> 3);   // XCD-bijective (512 % 8 == 0)
    const int bh  = wg >> 3;
    const int qg  = wg & 7;                          // 128-row group
    const int b   = bh >> 3;
    const int w    = threadIdx.x >> 6;
    const int lane = threadIdx.x & 63;
    const int col  = lane & 15;
    const int g    = lane >> 4;
    const float scale = 0.125f;

    if (w < 4) {
        // ======================= producers =======================
        const int pq  = w >> 1;
        const int khf = w & 1;
        const int kb  = khf * 512;
        const float* mb = mask + (size_t)b * SEQ + kb;
        const _Float16* kbase = Kh + ((size_t)bh * SEQ + kb + col) * DIM + g * 8;
        const _Float16* vtpb  = VTP + (((size_t)bh * 64 + khf * 32) * 64 + lane) * 16;

        f32x4 cprev[4];
        #pragma unroll
        for (int dt = 0; dt < 4; ++dt) cprev[dt] = (f32x4){0.f, 0.f, 0.f, 0.f};

        for (int t = 0; t < 4; ++t) {
            const int p  = t & 1;
            const int q0 = qg * 128 + t * 32;

            // finalize ctx of tile t-1 (khf==0 only; partner data crossed barrier)
            if (khf == 0 && t > 0) {
                const int pb  = (t - 1) & 1;
                const int q0p = qg * 128 + (t - 1) * 32;
                const float inv = 1.0f / (rs[pb][pq][0][col] + rs[pb][pq][1][col] + 1e-8f);
                #pragma unroll
                for (int dt = 0; dt < 4; ++dt) {
                    f32x4 r = cprev[dt];
                    #pragma unroll
                    for (int i = 0; i < 4; ++i) r[i] += cbuf[pb][pq][dt * 4 + i][lane];
                    r[0] *= inv; r[1] *= inv; r[2] *= inv; r[3] *= inv;
                    *(f32x4*)(ctx + ((size_t)bh * SEQ + q0p + pq * 16 + col) * DIM + dt * 16 + g * 4) = r;
                }
            }

            // ---- compute tile t
            f16x8 qf0, qf1;
            {
                const float* qp = Q + ((size_t)bh * SEQ + q0 + pq * 16 + col) * DIM + g * 8;
                qf0 = cvt8(*(const f32x4*)qp,        *(const f32x4*)(qp + 4));
                qf1 = cvt8(*(const f32x4*)(qp + 32), *(const f32x4*)(qp + 36));
            }
            f32x4 cacc[4];
            #pragma unroll
            for (int dt = 0; dt < 4; ++dt) cacc[dt] = (f32x4){0.f, 0.f, 0.f, 0.f};
            float rsum = 0.f;
            char* ebR = (char*)Ebuf[p] + (pq * 16 + col) * 2048;
            const int rx = (col & 3) << 2;   // row-XOR for granule swizzle

            f16x8 k0, k1, va, vb;
            f32x4 m4;
            if (PRECONV) {
                k0 = *(const f16x8*)(kbase);
                k1 = *(const f16x8*)(kbase + 32);
                va = *(const f16x8*)(vtpb);
                vb = *(const f16x8*)(vtpb + 8);
            } else {
                const float* kp = K + ((size_t)bh * SEQ + kb + col) * DIM + g * 8;
                k0 = cvt8(*(const f32x4*)kp,        *(const f32x4*)(kp + 4));
                k1 = cvt8(*(const f32x4*)(kp + 32), *(const f32x4*)(kp + 36));
                #pragma unroll
                for (int e = 0; e < 8; ++e) {
                    va[e] = (_Float16)V[((size_t)bh * SEQ + kb + g * 4 + (e & 3)) * DIM + (e >> 2) * 16 + col];
                    vb[e] = (_Float16)V[((size_t)bh * SEQ + kb + g * 4 + (e & 3)) * DIM + (2 + (e >> 2)) * 16 + col];
                }
            }
            m4 = *(const f32x4*)(mb + g * 4);

            // ROLLED loop (R15 fix): no #pragma unroll here.
            for (int kt = 0; kt < 32; ++kt) {
                const int ktn = (kt + 1) & 31;
                f16x8 n0, n1, nva, nvb;
                if (PRECONV) {
                    n0  = *(const f16x8*)(kbase + (size_t)ktn * 16 * DIM);
                    n1  = *(const f16x8*)(kbase + (size_t)ktn * 16 * DIM + 32);
                    nva = *(const f16x8*)(vtpb + (size_t)ktn * 64 * 16);
                    nvb = *(const f16x8*)(vtpb + (size_t)ktn * 64 * 16 + 8);
                } else {
                    const float* kp = K + ((size_t)bh * SEQ + kb + ktn * 16 + col) * DIM + g * 8;
                    n0 = cvt8(*(const f32x4*)kp,        *(const f32x4*)(kp + 4));
                    n1 = cvt8(*(const f32x4*)(kp + 32), *(const f32x4*)(kp + 36));
                    #pragma unroll
                    for (int e = 0; e < 8; ++e) {
                        nva[e] = (_Float16)V[((size_t)bh * SEQ + kb + ktn * 16 + g * 4 + (e & 3)) * DIM + (e >> 2) * 16 + col];
                        nvb[e] = (_Float16)V[((size_t)bh * SEQ + kb + ktn * 16 + g * 4 + (e & 3)) * DIM + (2 + (e >> 2)) * 16 + col];
                    }
                }
                f32x4 nm = *(const f32x4*)(mb + ktn * 16 + g * 4);

                f32x4 acc = {0.f, 0.f, 0.f, 0.f};
                acc = MFMA32(k0, qf0, acc);
                acc = MFMA32(k1, qf1, acc);
                const float e0 = __expf(acc[0] * scale) * m4[0];
                const float e1 = __expf(acc[1] * scale) * m4[1];
                const float e2 = __expf(acc[2] * scale) * m4[2];
                const float e3 = __expf(acc[3] * scale) * m4[3];
                rsum += e0 + e1 + e2 + e3;
                f16x4 pf;
                pf[0] = (_Float16)e0; pf[1] = (_Float16)e1;
                pf[2] = (_Float16)e2; pf[3] = (_Float16)e3;
                const int kg = (khf * 128 + kt * 4 + g) ^ rx;
                *(f16x4*)(ebR + kg * 8) = pf;

                {
                    f16x4 vt0 = __builtin_shufflevector(va, va, 0, 1, 2, 3);
                    f16x4 vt1 = __builtin_shufflevector(va, va, 4, 5, 6, 7);
                    f16x4 vt2 = __builtin_shufflevector(vb, vb, 0, 1, 2, 3);
                    f16x4 vt3 = __builtin_shufflevector(vb, vb, 4, 5, 6, 7);
                    cacc[0] = MFMA16(vt0, pf, cacc[0]);
                    cacc[1] = MFMA16(vt1, pf, cacc[1]);
                    cacc[2] = MFMA16(vt2, pf, cacc[2]);
                    cacc[3] = MFMA16(vt3, pf, cacc[3]);
                }
                k0 = n0; k1 = n1; va = nva; vb = nvb; m4 = nm;
            }

            rsum += __shfl_xor(rsum, 16, 64);
            rsum += __shfl_xor(rsum, 32, 64);
            if (g == 0) rs[p][pq][khf][col] = rsum;

            if (khf == 1) {
                #pragma unroll
                for (int dt = 0; dt < 4; ++dt)
                    #pragma unroll
                    for (int i = 0; i < 4; ++i)
                        cbuf[p][pq][dt * 4 + i][lane] = cacc[dt][i];
            } else {
                #pragma unroll
                for (int dt = 0; dt < 4; ++dt) cprev[dt] = cacc[dt];
            }
            __syncthreads();
        }

        // drain: finalize ctx of tile 3
        if (khf == 0) {
            const float inv = 1.0f / (rs[1][pq][0][col] + rs[1][pq][1][col] + 1e-8f);
            const int q0p = qg * 128 + 3 * 32;
            #pragma unroll
            for (int dt = 0; dt < 4; ++dt) {
                f32x4 r = cprev[dt];
                #pragma unroll
                for (int i = 0; i < 4; ++i) r[i] += cbuf[1][pq][dt * 4 + i][lane];
                r[0] *= inv; r[1] *= inv; r[2] *= inv; r[3] *= inv;
                *(f32x4*)(ctx + ((size_t)bh * SEQ + q0p + pq * 16 + col) * DIM + dt * 16 + g * 4) = r;
            }
        }
    } else {
        // ======================= consumers =======================
        const int cw = w - 4;
        for (int t = 0; t < 4; ++t) {
            if (t > 0) {
                const int pb  = (t - 1) & 1;
                const int q0p = qg * 128 + (t - 1) * 32;
                char* eb = (char*)Ebuf[pb];
                for (int j = 0; j < 8; ++j) {
                    const int r = cw * 8 + j;
                    const float inv = 1.0f / (rs[pb][r >> 4][0][r & 15] + rs[pb][r >> 4][1][r & 15] + 1e-8f);
                    f16x4 ev[4];
                    #pragma unroll
                    for (int q = 0; q < 4; ++q) {
                        const int kg = (q * 64 + lane) ^ ((r & 3) << 2);
                        ev[q] = *(const f16x4*)(eb + r * 2048 + kg * 8);
                    }
                    float* dst = scores + ((size_t)bh * SEQ + q0p + r) * SEQ + lane * 4;
                    #pragma unroll
                    for (int q = 0; q < 4; ++q) {
                        f32x4 o;
                        o[0] = (float)ev[q][0] * inv;
                        o[1] = (float)ev[q][1] * inv;
                        o[2] = (float)ev[q][2] * inv;
                        o[3] = (float)ev[q][3] * inv;
                        __builtin_nontemporal_store(o, (f32x4*)(dst + q * 256));
                    }
                }
            }
            __syncthreads();
        }
        // drain: flush tile 3
        {
            const int q0p = qg * 128 + 3 * 32;
            char* eb = (char*)Ebuf[1];
            for (int j = 0; j < 8; ++j) {
                const int r = cw * 8 + j;
                const float inv = 1.0f / (rs[1][r >> 4][0][r & 15] + rs[1][r >> 4][1][r & 15] + 1e-8f);
                f16x4 ev[4];
                #pragma unroll
                for (int q = 0; q < 4; ++q) {
                    const int kg = (q * 64 + lane) ^ ((r & 3) << 2);
                    ev[q] = *(const f16x4*)(eb + r * 2048 + kg * 8);
                }
                float* dst = scores + ((size_t)bh * SEQ + q0p + r) * SEQ + lane * 4;
                #pragma unroll
                for (int q = 0; q < 4; ++q) {
                    f32x4 o;
                    o[0] = (float)ev[q][0] * inv;
                    o[1] = (float)ev[q][1] * inv;
                    o[2] = (float)ev[q][2] * inv;
                    o[3] = (float)ev[q][3] * inv;
                    __builtin_nontemporal_store(o, (f32x4*)(dst + q * 256));
                }
            }
        }
    }
}

extern "C" void kernel_launch(void* const* d_in, const int* in_sizes, int n_in,
                              void* d_out, int out_size, void* d_ws, size_t ws_size,
                              hipStream_t stream)
{
    const float* Q    = (const float*)d_in[0];
    const float* K    = (const float*)d_in[1];
    const float* V    = (const float*)d_in[2];
    const float* mask = (const float*)d_in[3];
    float* ctx    = (float*)d_out;
    float* scores = ctx + (size_t)BHN * SEQ * DIM;

    const size_t elems = (size_t)BHN * SEQ * DIM;       // 4,194,304
    const size_t need  = elems * 2 * sizeof(_Float16);  // Kh + VTP = 16 MB
    if (ws_size >= need) {
        _Float16* Kh  = (_Float16*)d_ws;
        _Float16* VTP = Kh + elems;
        cvt_kv<<<512, 256, 0, stream>>>(K, V, Kh, VTP);
        attn_main<true><<<512, 512, 0, stream>>>(Q, K, V, mask, Kh, VTP, ctx, scores);
    } else {
        attn_main<false><<<512, 512, 0, stream>>>(Q, K, V, mask, nullptr, nullptr, ctx, scores);
    }
}

// Round 16
// 93.830 us; speedup vs baseline: 3.6799x; 1.3423x over previous
//
#include <hip/hip_runtime.h>

// B=8,H=8,S=1024,D=64 fp32 attention, raw-exp softmax, multiplicative key mask.
// Outputs: context[64,1024,64] then scores[64,1024,1024], both fp32.
// R16 = R9 (champion, 101 us) + two fixes:
//  (1) rowsums accumulated DURING compute (flush loses its per-row 64-lane
//      shfl-reduce chain; becomes pure LDS-read -> mul -> nt store).
//  (2) 2-deep software prefetch (named regs, loop pinned rolled) to cover
//      the full ~300cy L2 latency (1-deep covered only ~150cy).
// Kept: LDS-staged full-line nt flush (R11/R12 lessons), rolled loop (R10/13/14).

typedef float    f32x4 __attribute__((ext_vector_type(4)));
typedef _Float16 f16x8 __attribute__((ext_vector_type(8)));
typedef _Float16 f16x4 __attribute__((ext_vector_type(4)));

#define MFMA32(A, B, C) __builtin_amdgcn_mfma_f32_16x16x32_f16((A), (B), (C), 0, 0, 0)
#define MFMA16(A, B, C) __builtin_amdgcn_mfma_f32_16x16x16f16((A), (B), (C), 0, 0, 0)

#define BHN 64
#define SEQ 1024
#define DIM 64

__device__ inline f16x8 cvt8(f32x4 a, f32x4 b) {
    f16x8 r;
    r[0] = (_Float16)a[0]; r[1] = (_Float16)a[1]; r[2] = (_Float16)a[2]; r[3] = (_Float16)a[3];
    r[4] = (_Float16)b[0]; r[5] = (_Float16)b[1]; r[6] = (_Float16)b[2]; r[7] = (_Float16)b[3];
    return r;
}

// Pre-pass: K -> f16 same layout; V -> f16 repacked for PV:
// VTP[bh][ktg][lane][e], e=c*4+j : V[bh][ktg*16 + (lane>>4)*4 + j][c*16 + (lane&15)]
__global__ __launch_bounds__(256)
void cvt_kv(const float* __restrict__ K, const float* __restrict__ V,
            _Float16* __restrict__ Kh, _Float16* __restrict__ VTP)
{
    __shared__ _Float16 tile[128 * 65];
    const int bh = blockIdx.x >> 3;
    const int kc = blockIdx.x & 7;
    const int t  = threadIdx.x;
    const size_t base = ((size_t)bh * SEQ + (size_t)kc * 128) * DIM;

    for (int it = 0; it < 8; ++it) {
        int idx = it * 256 + t;
        int key = idx >> 4;
        int c4  = idx & 15;
        f32x4 kv = *(const f32x4*)(K + base + key * DIM + c4 * 4);
        f32x4 vv = *(const f32x4*)(V + base + key * DIM + c4 * 4);
        f16x4 kh4;
        kh4[0] = (_Float16)kv[0]; kh4[1] = (_Float16)kv[1];
        kh4[2] = (_Float16)kv[2]; kh4[3] = (_Float16)kv[3];
        *(f16x4*)(Kh + base + key * DIM + c4 * 4) = kh4;
        tile[key * 65 + c4 * 4 + 0] = (_Float16)vv[0];
        tile[key * 65 + c4 * 4 + 1] = (_Float16)vv[1];
        tile[key * 65 + c4 * 4 + 2] = (_Float16)vv[2];
        tile[key * 65 + c4 * 4 + 3] = (_Float16)vv[3];
    }
    __syncthreads();
    for (int it = 0; it < 8; ++it) {
        int flat = it * 256 + t;
        int ktl  = flat >> 8;
        int rem  = flat & 255;
        int l    = rem >> 2;
        int c    = rem & 3;
        f16x4 o;
        #pragma unroll
        for (int j = 0; j < 4; ++j)
            o[j] = tile[(ktl * 16 + ((l >> 4) << 2) + j) * 65 + c * 16 + (l & 15)];
        *(f16x4*)(VTP + (((size_t)bh * 64 + kc * 8 + ktl) * 64 + l) * 16 + c * 4) = o;
    }
}

// Main kernel. 2048 blocks x 256 thr. Block = 32 q-rows of one (b,h), all keys.
// Wave w owns key quarter. Swapped QK^T: lane qrow = lane&15, keys (lane>>4)*4+i.
// E staged f16 in 64 KB LDS (XOR-swizzled); rowsums accumulated in-loop.
template <bool PRECONV>
__global__ __launch_bounds__(256, 2)
void attn_main(const float* __restrict__ Q, const float* __restrict__ K,
               const float* __restrict__ V, const float* __restrict__ mask,
               const _Float16* __restrict__ Kh, const _Float16* __restrict__ VTP,
               float* __restrict__ ctx, float* __restrict__ scores)
{
    __shared__ _Float16 Et[32 * 1024];   // 64 KB
    __shared__ float rs[4][2][16];       // [wave][s][col] rowsum partials

    const int bid = blockIdx.x;
    const int wg  = ((bid & 7) << 8) | (bid >> 3);  // XCD-bijective (2048 % 8 == 0)
    const int bh  = wg >> 5;
    const int qb  = wg & 31;
    const int b   = bh >> 3;
    const int w    = threadIdx.x >> 6;   // key quarter
    const int lane = threadIdx.x & 63;
    const int col  = lane & 15;
    const int g    = lane >> 4;
    const int q0   = qb * 32;
    const int kb   = w * 256;
    const float scale = 0.125f;
    char* EtB = (char*)Et;

    // ---- Q fragments
    f16x8 qf[2][2];
    {
        const float* qbase = Q + ((size_t)bh * SEQ + q0) * DIM;
        #pragma unroll
        for (int s = 0; s < 2; ++s)
            #pragma unroll
            for (int f = 0; f < 2; ++f) {
                const float* p = qbase + (s * 16 + col) * DIM + f * 32 + g * 8;
                qf[s][f] = cvt8(*(const f32x4*)p, *(const f32x4*)(p + 4));
            }
    }
    const float* mb = mask + (size_t)b * SEQ + kb;
    const _Float16* kbase = Kh + ((size_t)bh * SEQ + kb + col) * DIM + g * 8;
    const _Float16* vtpb  = VTP + (((size_t)bh * 64 + w * 16) * 64 + lane) * 16;

    f32x4 cacc[2][4];
    #pragma unroll
    for (int s = 0; s < 2; ++s)
        #pragma unroll
        for (int dt = 0; dt < 4; ++dt) cacc[s][dt] = (f32x4){0.f, 0.f, 0.f, 0.f};
    float rsum[2] = {0.f, 0.f};

    auto loadS = [&](int kt, f16x8& a, f16x8& c, f16x8& x, f16x8& y, f32x4& m) {
        if (PRECONV) {
            a = *(const f16x8*)(kbase + (size_t)kt * 16 * DIM);
            c = *(const f16x8*)(kbase + (size_t)kt * 16 * DIM + 32);
            x = *(const f16x8*)(vtpb + (size_t)kt * 64 * 16);
            y = *(const f16x8*)(vtpb + (size_t)kt * 64 * 16 + 8);
        } else {
            const float* kp = K + ((size_t)bh * SEQ + kb + kt * 16 + col) * DIM + g * 8;
            a = cvt8(*(const f32x4*)kp,        *(const f32x4*)(kp + 4));
            c = cvt8(*(const f32x4*)(kp + 32), *(const f32x4*)(kp + 36));
            #pragma unroll
            for (int e = 0; e < 8; ++e) {
                x[e] = (_Float16)V[((size_t)bh * SEQ + kb + kt * 16 + g * 4 + (e & 3)) * DIM + (e >> 2) * 16 + col];
                y[e] = (_Float16)V[((size_t)bh * SEQ + kb + kt * 16 + g * 4 + (e & 3)) * DIM + (2 + (e >> 2)) * 16 + col];
            }
        }
        m = *(const f32x4*)(mb + kt * 16 + g * 4);
    };

    auto body = [&](int kt, f16x8 k0, f16x8 k1, f16x8 va, f16x8 vb, f32x4 m4) {
        f16x4 pf[2];
        #pragma unroll
        for (int s = 0; s < 2; ++s) {
            f32x4 acc = {0.f, 0.f, 0.f, 0.f};
            acc = MFMA32(k0, qf[s][0], acc);
            acc = MFMA32(k1, qf[s][1], acc);
            const float e0 = __expf(acc[0] * scale) * m4[0];
            const float e1 = __expf(acc[1] * scale) * m4[1];
            const float e2 = __expf(acc[2] * scale) * m4[2];
            const float e3 = __expf(acc[3] * scale) * m4[3];
            rsum[s] += e0 + e1 + e2 + e3;
            f16x4 eh;
            eh[0] = (_Float16)e0; eh[1] = (_Float16)e1;
            eh[2] = (_Float16)e2; eh[3] = (_Float16)e3;
            pf[s] = eh;
            const int row = s * 16 + col;
            const int kg  = (w * 64 + kt * 4 + g) ^ ((row & 3) << 2);
            *(f16x4*)(EtB + row * 2048 + kg * 8) = eh;
        }
        f16x4 vt0 = __builtin_shufflevector(va, va, 0, 1, 2, 3);
        f16x4 vt1 = __builtin_shufflevector(va, va, 4, 5, 6, 7);
        f16x4 vt2 = __builtin_shufflevector(vb, vb, 0, 1, 2, 3);
        f16x4 vt3 = __builtin_shufflevector(vb, vb, 4, 5, 6, 7);
        cacc[0][0] = MFMA16(vt0, pf[0], cacc[0][0]);
        cacc[1][0] = MFMA16(vt0, pf[1], cacc[1][0]);
        cacc[0][1] = MFMA16(vt1, pf[0], cacc[0][1]);
        cacc[1][1] = MFMA16(vt1, pf[1], cacc[1][1]);
        cacc[0][2] = MFMA16(vt2, pf[0], cacc[0][2]);
        cacc[1][2] = MFMA16(vt2, pf[1], cacc[1][2]);
        cacc[0][3] = MFMA16(vt3, pf[0], cacc[0][3]);
        cacc[1][3] = MFMA16(vt3, pf[1], cacc[1][3]);
    };

    // ---- 2-deep software pipeline over the 16 k-tiles (loop pinned rolled)
    f16x8 k0A, k1A, vaA, vbA, k0B, k1B, vaB, vbB;
    f32x4 m4A, m4B;
    loadS(0, k0A, k1A, vaA, vbA, m4A);
    loadS(1, k0B, k1B, vaB, vbB, m4B);

    #pragma unroll 1
    for (int kt = 0; kt < 16; kt += 2) {
        f16x8 n0, n1, nx, ny;
        f32x4 nm;
        loadS((kt + 2) & 15, n0, n1, nx, ny, nm);
        body(kt, k0A, k1A, vaA, vbA, m4A);
        k0A = n0; k1A = n1; vaA = nx; vbA = ny; m4A = nm;

        loadS((kt + 3) & 15, n0, n1, nx, ny, nm);
        body(kt + 1, k0B, k1B, vaB, vbB, m4B);
        k0B = n0; k1B = n1; vaB = nx; vbB = ny; m4B = nm;
    }

    // ---- rowsum partials -> LDS (replaces flush-phase shfl reduce)
    #pragma unroll
    for (int s = 0; s < 2; ++s) {
        float r = rsum[s];
        r += __shfl_xor(r, 16, 64);
        r += __shfl_xor(r, 32, 64);
        rsum[s] = r;
    }
    if (g == 0) {
        rs[w][0][col] = rsum[0];
        rs[w][1][col] = rsum[1];
    }
    __syncthreads();

    // ---- flush: wave w rows w*8..w*8+7; inv from rs (wave-uniform broadcast),
    // pure LDS-read -> mul -> nt full-line store. No cross-lane ops.
    const int r0 = w * 8;
    float* srow = scores + ((size_t)bh * SEQ + q0) * SEQ;
    for (int j = 0; j < 8; ++j) {
        const int r  = r0 + j;
        const int si = r >> 4, ci = r & 15;
        const float invr = 1.0f / (rs[0][si][ci] + rs[1][si][ci] + rs[2][si][ci] + rs[3][si][ci] + 1e-8f);
        f16x4 ev[4];
        #pragma unroll
        for (int q = 0; q < 4; ++q) {
            const int kg = (q * 64 + lane) ^ ((r & 3) << 2);
            ev[q] = *(const f16x4*)(EtB + r * 2048 + kg * 8);
        }
        float* dst = srow + (size_t)r * SEQ + lane * 4;
        #pragma unroll
        for (int q = 0; q < 4; ++q) {
            f32x4 o;
            o[0] = (float)ev[q][0] * invr;
            o[1] = (float)ev[q][1] * invr;
            o[2] = (float)ev[q][2] * invr;
            o[3] = (float)ev[q][3] * invr;
            __builtin_nontemporal_store(o, (f32x4*)(dst + q * 256));
        }
    }

    __syncthreads();

    // ---- PV combine epilogue: waves 1-3 dump raw cacc into dead E-tile,
    // wave 0 combines, scales by inv (recomputed from rs), writes ctx.
    float* dumpf = (float*)Et;
    if (w != 0) {
        float* d = dumpf + (w - 1) * 2048;
        #pragma unroll
        for (int s = 0; s < 2; ++s)
            #pragma unroll
            for (int dt = 0; dt < 4; ++dt)
                #pragma unroll
                for (int i = 0; i < 4; ++i)
                    d[((s * 4 + dt) * 4 + i) * 64 + lane] = cacc[s][dt][i];
    }
    __syncthreads();
    if (w == 0) {
        #pragma unroll
        for (int s = 0; s < 2; ++s) {
            const float invs = 1.0f / (rs[0][s][col] + rs[1][s][col] + rs[2][s][col] + rs[3][s][col] + 1e-8f);
            #pragma unroll
            for (int dt = 0; dt < 4; ++dt) {
                f32x4 r = cacc[s][dt];
                #pragma unroll
                for (int ww = 0; ww < 3; ++ww) {
                    const float* d = dumpf + ww * 2048;
                    #pragma unroll
                    for (int i = 0; i < 4; ++i)
                        r[i] += d[((s * 4 + dt) * 4 + i) * 64 + lane];
                }
                r[0] *= invs; r[1] *= invs; r[2] *= invs; r[3] *= invs;
                *(f32x4*)(ctx + ((size_t)bh * SEQ + q0 + s * 16 + col) * DIM + dt * 16 + g * 4) = r;
            }
        }
    }
}

extern "C" void kernel_launch(void* const* d_in, const int* in_sizes, int n_in,
                              void* d_out, int out_size, void* d_ws, size_t ws_size,
                              hipStream_t stream)
{
    const float* Q    = (const float*)d_in[0];
    const float* K    = (const float*)d_in[1];
    const float* V    = (const float*)d_in[2];
    const float* mask = (const float*)d_in[3];
    float* ctx    = (float*)d_out;
    float* scores = ctx + (size_t)BHN * SEQ * DIM;

    const size_t elems = (size_t)BHN * SEQ * DIM;       // 4,194,304
    const size_t need  = elems * 2 * sizeof(_Float16);  // Kh + VTP = 16 MB
    if (ws_size >= need) {
        _Float16* Kh  = (_Float16*)d_ws;
        _Float16* VTP = Kh + elems;
        cvt_kv<<<512, 256, 0, stream>>>(K, V, Kh, VTP);
        attn_main<true><<<2048, 256, 0, stream>>>(Q, K, V, mask, Kh, VTP, ctx, scores);
    } else {
        attn_main<false><<<2048, 256, 0, stream>>>(Q, K, V, mask, nullptr, nullptr, ctx, scores);
    }
}